// Round 9
// baseline (248.122 us; speedup 1.0000x reference)
//
#include <hip/hip_runtime.h>
#include <hip/hip_bf16.h>

// Problem: AdvancedAttentionLayer  B=2, S=2048, D=1024, H=16, DH=64
// Round 9: attn — double-buffered K/V staging with prefetch-at-top:
// 1 barrier/iter, staging latency hidden under compute (the vmcnt drain at
// the barrier now waits on loads issued a full compute-phase earlier).
// Mask row staged to LDS once (no per-iter global loads -> no vmcnt drain
// behind the prefetch). Everything else as round 8.

#define B_  2
#define S_  2048
#define D_  1024
#define K_  1024
#define H_  16
#define DH_ 64
#define BS_ (B_*S_)

typedef __hip_bfloat16 bf16;
typedef __attribute__((ext_vector_type(8))) short s8v;   // 8 bf16 = 4 VGPRs
typedef __attribute__((ext_vector_type(4))) short s4v;   // 4 bf16
typedef __attribute__((ext_vector_type(4))) float f4v;   // MFMA C/D

__device__ __forceinline__ float b2f(bf16 x) { return __bfloat162float(x); }
__device__ __forceinline__ bf16  f2b(float x) { return __float2bfloat16(x); }

__device__ __forceinline__ void gl_lds_16B(const bf16* g, bf16* l) {
    __builtin_amdgcn_global_load_lds(
        (const __attribute__((address_space(1))) unsigned int*)g,
        (__attribute__((address_space(3))) unsigned int*)l, 16, 0, 0);
}

// 0.125 * log2(e): folded QK^T scale so softmax uses raw exp2
#define QSCALE_ 0.1803368801f

// ---------------------------------------------------------------------------
// Prep 1: X fp32 -> bf16
// ---------------------------------------------------------------------------
__global__ __launch_bounds__(256) void convert_x_kernel(
    const float* __restrict__ X, bf16* __restrict__ Xb)
{
    const size_t idx = ((size_t)blockIdx.x * 256 + threadIdx.x) * 4;
    const float4 v = *(const float4*)(X + idx);
    bf16 t0 = f2b(v.x), t1 = f2b(v.y), t2 = f2b(v.z), t3 = f2b(v.w);
    s4v o;
    o[0] = *(short*)&t0; o[1] = *(short*)&t1;
    o[2] = *(short*)&t2; o[3] = *(short*)&t3;
    *(s4v*)(Xb + idx) = o;
}

// ---------------------------------------------------------------------------
// Prep 1b: mask int32 -> bf16 (0.0 / 1.0), [B*S]
// ---------------------------------------------------------------------------
__global__ __launch_bounds__(256) void convert_mask_kernel(
    const int* __restrict__ mask, bf16* __restrict__ mkbf)
{
    const int idx = blockIdx.x * 256 + threadIdx.x;
    mkbf[idx] = f2b(mask[idx] ? 1.0f : 0.0f);
}

// ---------------------------------------------------------------------------
// Prep 2: W [K][N] fp32 -> WT [N][K] bf16, 64x64 LDS tiles. z picks weight.
// ---------------------------------------------------------------------------
__global__ __launch_bounds__(256) void transpose_w_kernel(
    const float* __restrict__ Wq, const float* __restrict__ Wk,
    const float* __restrict__ Wv, const float* __restrict__ Wo,
    bf16* __restrict__ WTq, bf16* __restrict__ WTk,
    bf16* __restrict__ WTv, bf16* __restrict__ WTo)
{
    const int z = blockIdx.z;
    const float* __restrict__ W = (z == 0) ? Wq : (z == 1) ? Wk : (z == 2) ? Wv : Wo;
    bf16* __restrict__ WT       = (z == 0) ? WTq : (z == 1) ? WTk : (z == 2) ? WTv : WTo;

    const int k0 = blockIdx.x * 64;
    const int n0 = blockIdx.y * 64;

    __shared__ float Ls[64][68];

    const int t  = threadIdx.x;
    const int lr = t >> 4;
    const int lc = (t & 15) * 4;

    #pragma unroll
    for (int i = 0; i < 4; i++) {
        const int k = i * 16 + lr;
        const float4 v = *(const float4*)(W + (size_t)(k0 + k) * K_ + n0 + lc);
        Ls[k][lc + 0] = v.x; Ls[k][lc + 1] = v.y;
        Ls[k][lc + 2] = v.z; Ls[k][lc + 3] = v.w;
    }
    __syncthreads();
    #pragma unroll
    for (int i = 0; i < 4; i++) {
        const int n = i * 16 + lr;
        s4v o;
        #pragma unroll
        for (int j = 0; j < 4; j++) {
            bf16 tb = f2b(Ls[lc + j][n]);
            o[j] = *(short*)&tb;
        }
        *(s4v*)(WT + (size_t)(n0 + n) * K_ + k0 + lc) = o;
    }
}

// ---------------------------------------------------------------------------
// MFMA GEMM core, 128x128 tile (m97 structure). SWAPPED -> C^T layout.
// ---------------------------------------------------------------------------
template <bool SWAPPED>
__device__ __forceinline__ void gemm_tile(
    const bf16* __restrict__ A, const bf16* __restrict__ BT,
    int m0, int n0, bf16* As, bf16* Bs, f4v acc[4][4])
{
    const int t    = threadIdx.x;
    const int lane = t & 63;
    const int wave = t >> 6;
    const int quad = lane >> 4;
    const int l15  = lane & 15;
    const int wr   = wave >> 1;
    const int wc   = wave & 1;

    const int sr = t >> 3;
    const int sc = (t & 7) * 8;

    for (int kb = 0; kb < K_; kb += 64) {
        #pragma unroll
        for (int i = 0; i < 4; i++) {
            const int r = i * 32 + sr;
            gl_lds_16B(A  + (size_t)(m0 + r) * K_ + kb + sc, As + r * 64 + sc);
            gl_lds_16B(BT + (size_t)(n0 + r) * K_ + kb + sc, Bs + r * 64 + sc);
        }
        __syncthreads();

        #pragma unroll
        for (int ks = 0; ks < 2; ks++) {
            s8v fA[4], fB[4];
            #pragma unroll
            for (int i = 0; i < 4; i++) {
                fA[i] = *(const s8v*)&As[(wr * 64 + i * 16 + l15) * 64 + ks * 32 + quad * 8];
                fB[i] = *(const s8v*)&Bs[(wc * 64 + i * 16 + l15) * 64 + ks * 32 + quad * 8];
            }
            #pragma unroll
            for (int i = 0; i < 4; i++)
                #pragma unroll
                for (int j = 0; j < 4; j++)
                    acc[i][j] = SWAPPED
                        ? __builtin_amdgcn_mfma_f32_16x16x32_bf16(fB[i], fA[j], acc[i][j], 0, 0, 0)
                        : __builtin_amdgcn_mfma_f32_16x16x32_bf16(fA[i], fB[j], acc[i][j], 0, 0, 0);
        }
        __syncthreads();
    }
}

// ---------------------------------------------------------------------------
// QKV projection via MFMA. Grid (32, 8, 3), block 256.
// ---------------------------------------------------------------------------
__global__ __launch_bounds__(256) void proj_qkv_kernel(
    const bf16* __restrict__ Xb,
    const bf16* __restrict__ WTq, const float* __restrict__ bq,
    const bf16* __restrict__ WTk, const float* __restrict__ bk,
    const bf16* __restrict__ WTv, const float* __restrict__ bv,
    const float* __restrict__ emo, const int* __restrict__ mask,
    bf16* __restrict__ q_ws, bf16* __restrict__ k_ws, bf16* __restrict__ v_ws)
{
    const int m0 = blockIdx.x * 128;
    const int n0 = blockIdx.y * 128;
    const int z  = blockIdx.z;

    __shared__ __align__(16) bf16 As[128 * 64];
    __shared__ __align__(16) bf16 Bs[128 * 64];

    const int t    = threadIdx.x;
    const int lane = t & 63;
    const int wave = t >> 6;
    const int quad = lane >> 4;
    const int l15  = lane & 15;
    const int wr   = wave >> 1;
    const int wc   = wave & 1;

    f4v acc[4][4] = {};

    if (z == 0) {
        gemm_tile<false>(Xb, WTq, m0, n0, As, Bs, acc);
        #pragma unroll
        for (int j = 0; j < 4; j++) {
            const int n  = n0 + wc * 64 + j * 16 + l15;
            const int h  = n >> 6, dh = n & 63;
            const float bias_n = bq[n] + emo[n];
            #pragma unroll
            for (int i = 0; i < 4; i++) {
                #pragma unroll
                for (int r = 0; r < 4; r++) {
                    const int m = m0 + wr * 64 + i * 16 + quad * 4 + r;
                    const int b = m >> 11, s = m & 2047;
                    q_ws[(((size_t)(b * H_ + h)) * S_ + s) * DH_ + dh] =
                        f2b((acc[i][j][r] + bias_n) * QSCALE_);
                }
            }
        }
    } else if (z == 1) {
        gemm_tile<false>(Xb, WTk, m0, n0, As, Bs, acc);
        #pragma unroll
        for (int j = 0; j < 4; j++) {
            const int n  = n0 + wc * 64 + j * 16 + l15;
            const int h  = n >> 6, dh = n & 63;
            const float bias_n = bk[n];
            #pragma unroll
            for (int i = 0; i < 4; i++) {
                #pragma unroll
                for (int r = 0; r < 4; r++) {
                    const int m = m0 + wr * 64 + i * 16 + quad * 4 + r;
                    const int b = m >> 11, s = m & 2047;
                    k_ws[(((size_t)(b * H_ + h)) * S_ + s) * DH_ + dh] =
                        f2b(acc[i][j][r] + bias_n);
                }
            }
        }
    } else {
        gemm_tile<true>(Xb, WTv, m0, n0, As, Bs, acc);
        #pragma unroll
        for (int j = 0; j < 4; j++) {
            const int m = m0 + wr * 64 + j * 16 + l15;
            const int b = m >> 11, s = m & 2047;
            const float msk = mask[b * S_ + s] ? 1.0f : 0.0f;
            #pragma unroll
            for (int i = 0; i < 4; i++) {
                #pragma unroll
                for (int r = 0; r < 4; r++) {
                    const int n  = n0 + wc * 64 + i * 16 + quad * 4 + r;
                    const int h  = n >> 6, dh = n & 63;
                    v_ws[(((size_t)(b * H_ + h)) * DH_ + dh) * S_ + s] =
                        f2b((acc[i][j][r] + bv[n]) * msk);
                }
            }
        }
    }
}

// ---------------------------------------------------------------------------
// Output projection: 64x128 tile (grid 64x8 = 512 blocks = 2 wg/CU).
// ---------------------------------------------------------------------------
__global__ __launch_bounds__(256) void proj_out_kernel(
    const bf16* __restrict__ ctx, const bf16* __restrict__ WTo,
    const float* __restrict__ bo, float* __restrict__ out)
{
    const int m0 = blockIdx.x * 64;
    const int n0 = blockIdx.y * 128;

    __shared__ __align__(16) bf16 As[64 * 64];
    __shared__ __align__(16) bf16 Bs[128 * 64];

    const int t    = threadIdx.x;
    const int lane = t & 63;
    const int wave = t >> 6;
    const int quad = lane >> 4;
    const int l15  = lane & 15;
    const int wr   = wave >> 1;      // 0/1: 32-row half
    const int wc   = wave & 1;       // 0/1: 64-col half

    const int sr = t >> 3;
    const int sc = (t & 7) * 8;

    f4v acc[2][4] = {};

    for (int kb = 0; kb < K_; kb += 64) {
        #pragma unroll
        for (int i = 0; i < 2; i++) {
            const int r = i * 32 + sr;
            gl_lds_16B(ctx + (size_t)(m0 + r) * K_ + kb + sc, As + r * 64 + sc);
        }
        #pragma unroll
        for (int i = 0; i < 4; i++) {
            const int r = i * 32 + sr;
            gl_lds_16B(WTo + (size_t)(n0 + r) * K_ + kb + sc, Bs + r * 64 + sc);
        }
        __syncthreads();

        #pragma unroll
        for (int ks = 0; ks < 2; ks++) {
            s8v fA[2], fB[4];
            #pragma unroll
            for (int i = 0; i < 2; i++)
                fA[i] = *(const s8v*)&As[(wr * 32 + i * 16 + l15) * 64 + ks * 32 + quad * 8];
            #pragma unroll
            for (int j = 0; j < 4; j++)
                fB[j] = *(const s8v*)&Bs[(wc * 64 + j * 16 + l15) * 64 + ks * 32 + quad * 8];
            #pragma unroll
            for (int i = 0; i < 2; i++)
                #pragma unroll
                for (int j = 0; j < 4; j++)
                    acc[i][j] = __builtin_amdgcn_mfma_f32_16x16x32_bf16(fA[i], fB[j], acc[i][j], 0, 0, 0);
        }
        __syncthreads();
    }

    #pragma unroll
    for (int j = 0; j < 4; j++) {
        const int n = n0 + wc * 64 + j * 16 + l15;
        const float bias_n = bo[n];
        #pragma unroll
        for (int i = 0; i < 2; i++) {
            #pragma unroll
            for (int r = 0; r < 4; r++) {
                const int m = m0 + wr * 32 + i * 16 + quad * 4 + r;
                out[(size_t)m * D_ + n] = acc[i][j][r] + bias_n;
            }
        }
    }
}

// ---------------------------------------------------------------------------
// MFMA flash attention, round-9: double-buffered K/V, prefetch-at-top,
// 1 barrier/iter. Mask row in LDS (staged once). Fixed-base softmax.
// ---------------------------------------------------------------------------
#define PP_ 88   // p_lds row stride in bf16

__global__ __launch_bounds__(256) void attn_kernel(
    const bf16* __restrict__ q_ws, const bf16* __restrict__ k_ws,
    const bf16* __restrict__ v_ws, const bf16* __restrict__ mkbf,
    bf16* __restrict__ ctx)
{
    const int bh = blockIdx.x;
    const int q0 = blockIdx.y * 64;
    const int b  = bh >> 4;
    const int h  = bh & 15;

    __shared__ __align__(16) bf16 k_lds[2][64 * 64];   // [buf][key][d], swizzled
    __shared__ __align__(16) bf16 vt_lds[2][64 * 64];  // [buf][d][key], swizzled
    __shared__ __align__(16) bf16 p_lds[4][16 * PP_];  // per-wave [q][key]
    __shared__ __align__(16) bf16 mk_lds[S_];          // bf16 mask row for b

    const int t    = threadIdx.x;
    const int wave = t >> 6;
    const int lane = t & 63;
    const int quad = lane >> 4;
    const int l15  = lane & 15;
    const int lxor = l15 & 7;        // swizzle term for fragment reads

    // ---- Q as B-operand frags (q row = q0 + wave*16 + l15), direct global ----
    s8v qf[2];
    #pragma unroll
    for (int dt = 0; dt < 2; dt++)
        qf[dt] = *(const s8v*)(q_ws +
            ((size_t)bh * S_ + q0 + wave * 16 + l15) * DH_ + dt * 32 + quad * 8);

    f4v oacc[4] = {};        // O rows = q (quad*4+r), cols = dh (nt*16+l15)
    f4v osum   = {};         // denominator, same row layout

    // swizzled staging source/dest indices (per-lane constants)
    const bf16* kbase = k_ws + (size_t)bh * S_ * DH_;
    const bf16* vbase = v_ws + (size_t)bh * DH_ * S_;
    int off_l[2], off_k[2], off_v[2];
    #pragma unroll
    for (int c = 0; c < 2; c++) {
        const int e = c * 2048 + t * 8;
        const int r = e >> 6;                     // tile row
        const int cs = ((e >> 3) & 7) ^ (r & 7);  // source chunk (swizzled)
        off_l[c] = e;
        off_k[c] = r * 64 + cs * 8;
        off_v[c] = r * S_ + cs * 8;
    }

    // ---- stage mask row (once) and first K/V tile into buf 0 ----
    gl_lds_16B(mkbf + (size_t)b * S_ + t * 8, mk_lds + t * 8);
    #pragma unroll
    for (int c = 0; c < 2; c++) {
        gl_lds_16B(kbase + off_k[c], &k_lds[0][off_l[c]]);
        gl_lds_16B(vbase + off_v[c], &vt_lds[0][off_l[c]]);
    }

    for (int it = 0; it < S_ / 64; it++) {
        const int cur = it & 1;
        __syncthreads();   // drains vmcnt: loads for buf[cur] (issued an entire
                           // compute-phase ago for it>0) + syncs buffer reuse

        // ---- prefetch next tile into the other buffer ----
        if (it + 1 < S_ / 64) {
            const int nk = (it + 1) * 4096;   // elem step: 64 keys * 64 d
            const int nv = (it + 1) * 64;
            #pragma unroll
            for (int c = 0; c < 2; c++) {
                gl_lds_16B(kbase + nk + off_k[c], &k_lds[cur ^ 1][off_l[c]]);
                gl_lds_16B(vbase + nv + off_v[c], &vt_lds[cur ^ 1][off_l[c]]);
            }
        }

        // ---- S^T = K Q^T : 4 key-tiles x 2 d-halves ----
        f4v sacc[4] = {};
        #pragma unroll
        for (int kt = 0; kt < 4; kt++) {
            #pragma unroll
            for (int dt = 0; dt < 2; dt++) {
                const s8v kf = *(const s8v*)&k_lds[cur][(kt * 16 + l15) * 64 +
                                                        ((dt * 4 + quad) ^ lxor) * 8];
                sacc[kt] = __builtin_amdgcn_mfma_f32_16x16x32_bf16(kf, qf[dt], sacc[kt], 0, 0, 0);
            }
        }

        // ---- fixed-base softmax numerators: p = exp2(s), straight to LDS ----
        #pragma unroll
        for (int kt = 0; kt < 4; kt++) {
            float2 e01, e23;
            e01.x = exp2f(sacc[kt][0]);
            e01.y = exp2f(sacc[kt][1]);
            e23.x = exp2f(sacc[kt][2]);
            e23.y = exp2f(sacc[kt][3]);
            union { __hip_bfloat162 hh; unsigned u; } lo, hi;
            lo.hh = __float22bfloat162_rn(e01);
            hi.hh = __float22bfloat162_rn(e23);
            *(uint2*)&p_lds[wave][l15 * PP_ + kt * 16 + quad * 4] =
                make_uint2(lo.u, hi.u);
        }

        // p_lds is wave-private: wait LDS only (lgkmcnt(0)); prefetch vmcnt
        // stays outstanding.
        __builtin_amdgcn_s_waitcnt(0xC07F);

        // ---- O += P V ; denominator += P maskvec (from LDS) ----
        #pragma unroll
        for (int kh = 0; kh < 2; kh++) {
            const s8v ap = *(const s8v*)&p_lds[wave][l15 * PP_ + kh * 32 + quad * 8];
            const s8v mv = *(const s8v*)&mk_lds[it * 64 + kh * 32 + quad * 8];
            #pragma unroll
            for (int nt = 0; nt < 4; nt++) {
                const s8v vf = *(const s8v*)&vt_lds[cur][(nt * 16 + l15) * 64 +
                                                         ((kh * 4 + quad) ^ lxor) * 8];
                oacc[nt] = __builtin_amdgcn_mfma_f32_16x16x32_bf16(ap, vf, oacc[nt], 0, 0, 0);
            }
            osum = __builtin_amdgcn_mfma_f32_16x16x32_bf16(ap, mv, osum, 0, 0, 0);
        }
    }

    // ---- epilogue ----
    #pragma unroll
    for (int r = 0; r < 4; r++) {
        const float inv = 1.0f / osum[r];
        const int q = q0 + wave * 16 + quad * 4 + r;
        #pragma unroll
        for (int nt = 0; nt < 4; nt++)
            ctx[((size_t)b * S_ + q) * D_ + h * DH_ + nt * 16 + l15] =
                f2b(oacc[nt][r] * inv);
    }
}

// ---------------------------------------------------------------------------
extern "C" void kernel_launch(void* const* d_in, const int* in_sizes, int n_in,
                              void* d_out, int out_size, void* d_ws, size_t ws_size,
                              hipStream_t stream) {
    (void)in_sizes; (void)n_in; (void)out_size; (void)ws_size;

    const float* X    = (const float*)d_in[0];
    const int*   mask = (const int*)d_in[1];
    const float* Wq   = (const float*)d_in[2];
    const float* bq   = (const float*)d_in[3];
    const float* Wk   = (const float*)d_in[4];
    const float* bk   = (const float*)d_in[5];
    const float* Wv   = (const float*)d_in[6];
    const float* bv   = (const float*)d_in[7];
    const float* emo  = (const float*)d_in[8];
    const float* Wo   = (const float*)d_in[9];
    const float* bo   = (const float*)d_in[10];
    float* out = (float*)d_out;

    bf16* q_ws = (bf16*)d_ws;                       // [B,H,S,DH]   8 MB
    bf16* k_ws = q_ws + (size_t)BS_ * D_;           // [B,H,S,DH]   8 MB
    bf16* v_ws = k_ws + (size_t)BS_ * D_;           // [B,H,DH,S]   8 MB
    bf16* ctx  = v_ws + (size_t)BS_ * D_;           // [B,S,D]      8 MB
    bf16* Xb   = ctx  + (size_t)BS_ * D_;           // [BS,D]       8 MB
    bf16* WTq  = Xb   + (size_t)BS_ * D_;           // [N,K]        2 MB
    bf16* WTk  = WTq  + (size_t)D_ * K_;
    bf16* WTv  = WTk  + (size_t)D_ * K_;
    bf16* WTo  = WTv  + (size_t)D_ * K_;
    bf16* mkbf = WTo  + (size_t)D_ * K_;            // [B*S] bf16 mask

    hipLaunchKernelGGL(convert_x_kernel, dim3(BS_ * D_ / 1024), dim3(256), 0, stream, X, Xb);
    hipLaunchKernelGGL(convert_mask_kernel, dim3(BS_ / 256), dim3(256), 0, stream, mask, mkbf);
    hipLaunchKernelGGL(transpose_w_kernel, dim3(K_ / 64, D_ / 64, 4), dim3(256), 0, stream,
                       Wq, Wk, Wv, Wo, WTq, WTk, WTv, WTo);
    hipLaunchKernelGGL(proj_qkv_kernel, dim3(BS_ / 128, D_ / 128, 3), dim3(256), 0, stream,
                       Xb, WTq, bq, WTk, bk, WTv, bv, emo, mask, q_ws, k_ws, v_ws);
    hipLaunchKernelGGL(attn_kernel, dim3(B_ * H_, S_ / 64), dim3(256), 0, stream,
                       q_ws, k_ws, v_ws, mkbf, ctx);
    hipLaunchKernelGGL(proj_out_kernel, dim3(BS_ / 64, D_ / 128), dim3(256), 0, stream,
                       ctx, WTo, bo, out);
}

// Round 10
// 233.937 us; speedup vs baseline: 1.0606x; 1.0606x over previous
//
#include <hip/hip_runtime.h>
#include <hip/hip_bf16.h>

// Problem: AdvancedAttentionLayer  B=2, S=2048, D=1024, H=16, DH=64
// Round 10: attn — round-8 structure (single-buffer, 2 barriers/iter,
// fixed-base softmax) with a 128-q-row block tile: 2 q-subtiles per wave,
// grid (32,16). Staging traffic, LDS writes, and barriers per q-row halve;
// 36 MFMA per wave-iter. Double-buffer (r9) reverted: occupancy > latency.

#define B_  2
#define S_  2048
#define D_  1024
#define K_  1024
#define H_  16
#define DH_ 64
#define BS_ (B_*S_)

typedef __hip_bfloat16 bf16;
typedef __attribute__((ext_vector_type(8))) short s8v;   // 8 bf16 = 4 VGPRs
typedef __attribute__((ext_vector_type(4))) short s4v;   // 4 bf16
typedef __attribute__((ext_vector_type(4))) float f4v;   // MFMA C/D

__device__ __forceinline__ float b2f(bf16 x) { return __bfloat162float(x); }
__device__ __forceinline__ bf16  f2b(float x) { return __float2bfloat16(x); }

__device__ __forceinline__ void gl_lds_16B(const bf16* g, bf16* l) {
    __builtin_amdgcn_global_load_lds(
        (const __attribute__((address_space(1))) unsigned int*)g,
        (__attribute__((address_space(3))) unsigned int*)l, 16, 0, 0);
}

// 0.125 * log2(e): folded QK^T scale so softmax uses raw exp2
#define QSCALE_ 0.1803368801f

// ---------------------------------------------------------------------------
// Prep 1: X fp32 -> bf16
// ---------------------------------------------------------------------------
__global__ __launch_bounds__(256) void convert_x_kernel(
    const float* __restrict__ X, bf16* __restrict__ Xb)
{
    const size_t idx = ((size_t)blockIdx.x * 256 + threadIdx.x) * 4;
    const float4 v = *(const float4*)(X + idx);
    bf16 t0 = f2b(v.x), t1 = f2b(v.y), t2 = f2b(v.z), t3 = f2b(v.w);
    s4v o;
    o[0] = *(short*)&t0; o[1] = *(short*)&t1;
    o[2] = *(short*)&t2; o[3] = *(short*)&t3;
    *(s4v*)(Xb + idx) = o;
}

// ---------------------------------------------------------------------------
// Prep 1b: mask int32 -> bf16 (0.0 / 1.0), [B*S]
// ---------------------------------------------------------------------------
__global__ __launch_bounds__(256) void convert_mask_kernel(
    const int* __restrict__ mask, bf16* __restrict__ mkbf)
{
    const int idx = blockIdx.x * 256 + threadIdx.x;
    mkbf[idx] = f2b(mask[idx] ? 1.0f : 0.0f);
}

// ---------------------------------------------------------------------------
// Prep 2: W [K][N] fp32 -> WT [N][K] bf16, 64x64 LDS tiles. z picks weight.
// ---------------------------------------------------------------------------
__global__ __launch_bounds__(256) void transpose_w_kernel(
    const float* __restrict__ Wq, const float* __restrict__ Wk,
    const float* __restrict__ Wv, const float* __restrict__ Wo,
    bf16* __restrict__ WTq, bf16* __restrict__ WTk,
    bf16* __restrict__ WTv, bf16* __restrict__ WTo)
{
    const int z = blockIdx.z;
    const float* __restrict__ W = (z == 0) ? Wq : (z == 1) ? Wk : (z == 2) ? Wv : Wo;
    bf16* __restrict__ WT       = (z == 0) ? WTq : (z == 1) ? WTk : (z == 2) ? WTv : WTo;

    const int k0 = blockIdx.x * 64;
    const int n0 = blockIdx.y * 64;

    __shared__ float Ls[64][68];

    const int t  = threadIdx.x;
    const int lr = t >> 4;
    const int lc = (t & 15) * 4;

    #pragma unroll
    for (int i = 0; i < 4; i++) {
        const int k = i * 16 + lr;
        const float4 v = *(const float4*)(W + (size_t)(k0 + k) * K_ + n0 + lc);
        Ls[k][lc + 0] = v.x; Ls[k][lc + 1] = v.y;
        Ls[k][lc + 2] = v.z; Ls[k][lc + 3] = v.w;
    }
    __syncthreads();
    #pragma unroll
    for (int i = 0; i < 4; i++) {
        const int n = i * 16 + lr;
        s4v o;
        #pragma unroll
        for (int j = 0; j < 4; j++) {
            bf16 tb = f2b(Ls[lc + j][n]);
            o[j] = *(short*)&tb;
        }
        *(s4v*)(WT + (size_t)(n0 + n) * K_ + k0 + lc) = o;
    }
}

// ---------------------------------------------------------------------------
// MFMA GEMM core, 128x128 tile (m97 structure). SWAPPED -> C^T layout.
// ---------------------------------------------------------------------------
template <bool SWAPPED>
__device__ __forceinline__ void gemm_tile(
    const bf16* __restrict__ A, const bf16* __restrict__ BT,
    int m0, int n0, bf16* As, bf16* Bs, f4v acc[4][4])
{
    const int t    = threadIdx.x;
    const int lane = t & 63;
    const int wave = t >> 6;
    const int quad = lane >> 4;
    const int l15  = lane & 15;
    const int wr   = wave >> 1;
    const int wc   = wave & 1;

    const int sr = t >> 3;
    const int sc = (t & 7) * 8;

    for (int kb = 0; kb < K_; kb += 64) {
        #pragma unroll
        for (int i = 0; i < 4; i++) {
            const int r = i * 32 + sr;
            gl_lds_16B(A  + (size_t)(m0 + r) * K_ + kb + sc, As + r * 64 + sc);
            gl_lds_16B(BT + (size_t)(n0 + r) * K_ + kb + sc, Bs + r * 64 + sc);
        }
        __syncthreads();

        #pragma unroll
        for (int ks = 0; ks < 2; ks++) {
            s8v fA[4], fB[4];
            #pragma unroll
            for (int i = 0; i < 4; i++) {
                fA[i] = *(const s8v*)&As[(wr * 64 + i * 16 + l15) * 64 + ks * 32 + quad * 8];
                fB[i] = *(const s8v*)&Bs[(wc * 64 + i * 16 + l15) * 64 + ks * 32 + quad * 8];
            }
            #pragma unroll
            for (int i = 0; i < 4; i++)
                #pragma unroll
                for (int j = 0; j < 4; j++)
                    acc[i][j] = SWAPPED
                        ? __builtin_amdgcn_mfma_f32_16x16x32_bf16(fB[i], fA[j], acc[i][j], 0, 0, 0)
                        : __builtin_amdgcn_mfma_f32_16x16x32_bf16(fA[i], fB[j], acc[i][j], 0, 0, 0);
        }
        __syncthreads();
    }
}

// ---------------------------------------------------------------------------
// QKV projection via MFMA. Grid (32, 8, 3), block 256.
// ---------------------------------------------------------------------------
__global__ __launch_bounds__(256) void proj_qkv_kernel(
    const bf16* __restrict__ Xb,
    const bf16* __restrict__ WTq, const float* __restrict__ bq,
    const bf16* __restrict__ WTk, const float* __restrict__ bk,
    const bf16* __restrict__ WTv, const float* __restrict__ bv,
    const float* __restrict__ emo, const int* __restrict__ mask,
    bf16* __restrict__ q_ws, bf16* __restrict__ k_ws, bf16* __restrict__ v_ws)
{
    const int m0 = blockIdx.x * 128;
    const int n0 = blockIdx.y * 128;
    const int z  = blockIdx.z;

    __shared__ __align__(16) bf16 As[128 * 64];
    __shared__ __align__(16) bf16 Bs[128 * 64];

    const int t    = threadIdx.x;
    const int lane = t & 63;
    const int wave = t >> 6;
    const int quad = lane >> 4;
    const int l15  = lane & 15;
    const int wr   = wave >> 1;
    const int wc   = wave & 1;

    f4v acc[4][4] = {};

    if (z == 0) {
        gemm_tile<false>(Xb, WTq, m0, n0, As, Bs, acc);
        #pragma unroll
        for (int j = 0; j < 4; j++) {
            const int n  = n0 + wc * 64 + j * 16 + l15;
            const int h  = n >> 6, dh = n & 63;
            const float bias_n = bq[n] + emo[n];
            #pragma unroll
            for (int i = 0; i < 4; i++) {
                #pragma unroll
                for (int r = 0; r < 4; r++) {
                    const int m = m0 + wr * 64 + i * 16 + quad * 4 + r;
                    const int b = m >> 11, s = m & 2047;
                    q_ws[(((size_t)(b * H_ + h)) * S_ + s) * DH_ + dh] =
                        f2b((acc[i][j][r] + bias_n) * QSCALE_);
                }
            }
        }
    } else if (z == 1) {
        gemm_tile<false>(Xb, WTk, m0, n0, As, Bs, acc);
        #pragma unroll
        for (int j = 0; j < 4; j++) {
            const int n  = n0 + wc * 64 + j * 16 + l15;
            const int h  = n >> 6, dh = n & 63;
            const float bias_n = bk[n];
            #pragma unroll
            for (int i = 0; i < 4; i++) {
                #pragma unroll
                for (int r = 0; r < 4; r++) {
                    const int m = m0 + wr * 64 + i * 16 + quad * 4 + r;
                    const int b = m >> 11, s = m & 2047;
                    k_ws[(((size_t)(b * H_ + h)) * S_ + s) * DH_ + dh] =
                        f2b(acc[i][j][r] + bias_n);
                }
            }
        }
    } else {
        gemm_tile<true>(Xb, WTv, m0, n0, As, Bs, acc);
        #pragma unroll
        for (int j = 0; j < 4; j++) {
            const int m = m0 + wr * 64 + j * 16 + l15;
            const int b = m >> 11, s = m & 2047;
            const float msk = mask[b * S_ + s] ? 1.0f : 0.0f;
            #pragma unroll
            for (int i = 0; i < 4; i++) {
                #pragma unroll
                for (int r = 0; r < 4; r++) {
                    const int n  = n0 + wc * 64 + i * 16 + quad * 4 + r;
                    const int h  = n >> 6, dh = n & 63;
                    v_ws[(((size_t)(b * H_ + h)) * DH_ + dh) * S_ + s] =
                        f2b((acc[i][j][r] + bv[n]) * msk);
                }
            }
        }
    }
}

// ---------------------------------------------------------------------------
// Output projection: 64x128 tile (grid 64x8 = 512 blocks = 2 wg/CU).
// ---------------------------------------------------------------------------
__global__ __launch_bounds__(256) void proj_out_kernel(
    const bf16* __restrict__ ctx, const bf16* __restrict__ WTo,
    const float* __restrict__ bo, float* __restrict__ out)
{
    const int m0 = blockIdx.x * 64;
    const int n0 = blockIdx.y * 128;

    __shared__ __align__(16) bf16 As[64 * 64];
    __shared__ __align__(16) bf16 Bs[128 * 64];

    const int t    = threadIdx.x;
    const int lane = t & 63;
    const int wave = t >> 6;
    const int quad = lane >> 4;
    const int l15  = lane & 15;
    const int wr   = wave >> 1;      // 0/1: 32-row half
    const int wc   = wave & 1;       // 0/1: 64-col half

    const int sr = t >> 3;
    const int sc = (t & 7) * 8;

    f4v acc[2][4] = {};

    for (int kb = 0; kb < K_; kb += 64) {
        #pragma unroll
        for (int i = 0; i < 2; i++) {
            const int r = i * 32 + sr;
            gl_lds_16B(ctx + (size_t)(m0 + r) * K_ + kb + sc, As + r * 64 + sc);
        }
        #pragma unroll
        for (int i = 0; i < 4; i++) {
            const int r = i * 32 + sr;
            gl_lds_16B(WTo + (size_t)(n0 + r) * K_ + kb + sc, Bs + r * 64 + sc);
        }
        __syncthreads();

        #pragma unroll
        for (int ks = 0; ks < 2; ks++) {
            s8v fA[2], fB[4];
            #pragma unroll
            for (int i = 0; i < 2; i++)
                fA[i] = *(const s8v*)&As[(wr * 32 + i * 16 + l15) * 64 + ks * 32 + quad * 8];
            #pragma unroll
            for (int j = 0; j < 4; j++)
                fB[j] = *(const s8v*)&Bs[(wc * 64 + j * 16 + l15) * 64 + ks * 32 + quad * 8];
            #pragma unroll
            for (int i = 0; i < 2; i++)
                #pragma unroll
                for (int j = 0; j < 4; j++)
                    acc[i][j] = __builtin_amdgcn_mfma_f32_16x16x32_bf16(fA[i], fB[j], acc[i][j], 0, 0, 0);
        }
        __syncthreads();
    }

    #pragma unroll
    for (int j = 0; j < 4; j++) {
        const int n = n0 + wc * 64 + j * 16 + l15;
        const float bias_n = bo[n];
        #pragma unroll
        for (int i = 0; i < 2; i++) {
            #pragma unroll
            for (int r = 0; r < 4; r++) {
                const int m = m0 + wr * 32 + i * 16 + quad * 4 + r;
                out[(size_t)m * D_ + n] = acc[i][j][r] + bias_n;
            }
        }
    }
}

// ---------------------------------------------------------------------------
// MFMA flash attention, round-10: r8 structure, 128 q-rows/block.
// Grid (B*H=32, S/128=16), block 256 = 4 waves; wave owns 32 q (2 subtiles).
// ---------------------------------------------------------------------------
#define PP_ 88   // p_lds row stride in bf16

__global__ __launch_bounds__(256) void attn_kernel(
    const bf16* __restrict__ q_ws, const bf16* __restrict__ k_ws,
    const bf16* __restrict__ v_ws, const bf16* __restrict__ mkbf,
    bf16* __restrict__ ctx)
{
    const int bh = blockIdx.x;
    const int q0 = blockIdx.y * 128;
    const int b  = bh >> 4;
    const int h  = bh & 15;

    __shared__ __align__(16) bf16 k_lds[64 * 64];     // [key][d], swizzled
    __shared__ __align__(16) bf16 vt_lds[64 * 64];    // [d][key], swizzled
    __shared__ __align__(16) bf16 p_lds[4][32 * PP_]; // per-wave [q][key]

    const int t    = threadIdx.x;
    const int wave = t >> 6;
    const int lane = t & 63;
    const int quad = lane >> 4;
    const int l15  = lane & 15;
    const int lxor = l15 & 7;        // swizzle term for fragment reads

    // ---- Q as B-operand frags (q = q0 + wave*32 + qs*16 + l15), global ----
    s8v qf[2][2];
    #pragma unroll
    for (int qs = 0; qs < 2; qs++)
        #pragma unroll
        for (int dt = 0; dt < 2; dt++)
            qf[qs][dt] = *(const s8v*)(q_ws +
                ((size_t)bh * S_ + q0 + wave * 32 + qs * 16 + l15) * DH_ + dt * 32 + quad * 8);

    f4v oacc[2][4] = {};     // [qs][nt]: rows q (quad*4+r), cols dh (nt*16+l15)
    f4v osum[2]    = {};     // denominators

    // swizzled staging source indices (per-lane constants)
    int srw[2], scs[2];
    #pragma unroll
    for (int c = 0; c < 2; c++) {
        const int e = c * 2048 + t * 8;
        srw[c] = e >> 6;                          // tile row
        scs[c] = ((e >> 3) & 7) ^ (srw[c] & 7);   // source chunk (swizzled)
    }

    for (int kb0 = 0; kb0 < S_; kb0 += 64) {
        // ---- stage K, Vt via global_load_lds with XOR-swizzled sources ----
        #pragma unroll
        for (int c = 0; c < 2; c++) {
            const int e = c * 2048 + t * 8;
            const int r = srw[c], cs = scs[c];
            gl_lds_16B(k_ws + ((size_t)bh * S_ + kb0) * DH_ + r * 64 + cs * 8,
                       k_lds + e);
            gl_lds_16B(v_ws + ((size_t)bh * DH_ + r) * S_ + kb0 + cs * 8,
                       vt_lds + e);
        }
        __syncthreads();

        // ---- S^T = K Q^T : 4 key-tiles x 2 d-halves x 2 q-subtiles ----
        f4v sacc[2][4] = {};
        #pragma unroll
        for (int kt = 0; kt < 4; kt++) {
            #pragma unroll
            for (int dt = 0; dt < 2; dt++) {
                const s8v kf = *(const s8v*)&k_lds[(kt * 16 + l15) * 64 +
                                                   ((dt * 4 + quad) ^ lxor) * 8];
                #pragma unroll
                for (int qs = 0; qs < 2; qs++)
                    sacc[qs][kt] = __builtin_amdgcn_mfma_f32_16x16x32_bf16(kf, qf[qs][dt], sacc[qs][kt], 0, 0, 0);
            }
        }

        // ---- fixed-base softmax numerators: p = exp2(s), straight to LDS ----
        #pragma unroll
        for (int qs = 0; qs < 2; qs++) {
            #pragma unroll
            for (int kt = 0; kt < 4; kt++) {
                float2 e01, e23;
                e01.x = exp2f(sacc[qs][kt][0]);
                e01.y = exp2f(sacc[qs][kt][1]);
                e23.x = exp2f(sacc[qs][kt][2]);
                e23.y = exp2f(sacc[qs][kt][3]);
                union { __hip_bfloat162 hh; unsigned u; } lo, hi;
                lo.hh = __float22bfloat162_rn(e01);
                hi.hh = __float22bfloat162_rn(e23);
                *(uint2*)&p_lds[wave][(qs * 16 + l15) * PP_ + kt * 16 + quad * 4] =
                    make_uint2(lo.u, hi.u);
            }
        }

        // p_lds is wave-private: need only LDS drain, no barrier
        __builtin_amdgcn_s_waitcnt(0xC07F);

        // ---- O += P V ; denominator += P maskvec ----
        #pragma unroll
        for (int kh = 0; kh < 2; kh++) {
            s8v ap[2];
            #pragma unroll
            for (int qs = 0; qs < 2; qs++)
                ap[qs] = *(const s8v*)&p_lds[wave][(qs * 16 + l15) * PP_ + kh * 32 + quad * 8];
            const s8v mv = *(const s8v*)(mkbf + (size_t)b * S_ + kb0 + kh * 32 + quad * 8);
            #pragma unroll
            for (int nt = 0; nt < 4; nt++) {
                const s8v vf = *(const s8v*)&vt_lds[(nt * 16 + l15) * 64 +
                                                    ((kh * 4 + quad) ^ lxor) * 8];
                #pragma unroll
                for (int qs = 0; qs < 2; qs++)
                    oacc[qs][nt] = __builtin_amdgcn_mfma_f32_16x16x32_bf16(ap[qs], vf, oacc[qs][nt], 0, 0, 0);
            }
            #pragma unroll
            for (int qs = 0; qs < 2; qs++)
                osum[qs] = __builtin_amdgcn_mfma_f32_16x16x32_bf16(ap[qs], mv, osum[qs], 0, 0, 0);
        }
        __syncthreads();   // protect k_lds/vt_lds before next staging
    }

    // ---- epilogue ----
    #pragma unroll
    for (int qs = 0; qs < 2; qs++) {
        #pragma unroll
        for (int r = 0; r < 4; r++) {
            const float inv = 1.0f / osum[qs][r];
            const int q = q0 + wave * 32 + qs * 16 + quad * 4 + r;
            #pragma unroll
            for (int nt = 0; nt < 4; nt++)
                ctx[((size_t)b * S_ + q) * D_ + h * DH_ + nt * 16 + l15] =
                    f2b(oacc[qs][nt][r] * inv);
        }
    }
}

// ---------------------------------------------------------------------------
extern "C" void kernel_launch(void* const* d_in, const int* in_sizes, int n_in,
                              void* d_out, int out_size, void* d_ws, size_t ws_size,
                              hipStream_t stream) {
    (void)in_sizes; (void)n_in; (void)out_size; (void)ws_size;

    const float* X    = (const float*)d_in[0];
    const int*   mask = (const int*)d_in[1];
    const float* Wq   = (const float*)d_in[2];
    const float* bq   = (const float*)d_in[3];
    const float* Wk   = (const float*)d_in[4];
    const float* bk   = (const float*)d_in[5];
    const float* Wv   = (const float*)d_in[6];
    const float* bv   = (const float*)d_in[7];
    const float* emo  = (const float*)d_in[8];
    const float* Wo   = (const float*)d_in[9];
    const float* bo   = (const float*)d_in[10];
    float* out = (float*)d_out;

    bf16* q_ws = (bf16*)d_ws;                       // [B,H,S,DH]   8 MB
    bf16* k_ws = q_ws + (size_t)BS_ * D_;           // [B,H,S,DH]   8 MB
    bf16* v_ws = k_ws + (size_t)BS_ * D_;           // [B,H,DH,S]   8 MB
    bf16* ctx  = v_ws + (size_t)BS_ * D_;           // [B,S,D]      8 MB
    bf16* Xb   = ctx  + (size_t)BS_ * D_;           // [BS,D]       8 MB
    bf16* WTq  = Xb   + (size_t)BS_ * D_;           // [N,K]        2 MB
    bf16* WTk  = WTq  + (size_t)D_ * K_;
    bf16* WTv  = WTk  + (size_t)D_ * K_;
    bf16* WTo  = WTv  + (size_t)D_ * K_;
    bf16* mkbf = WTo  + (size_t)D_ * K_;            // [B*S] bf16 mask

    hipLaunchKernelGGL(convert_x_kernel, dim3(BS_ * D_ / 1024), dim3(256), 0, stream, X, Xb);
    hipLaunchKernelGGL(convert_mask_kernel, dim3(BS_ / 256), dim3(256), 0, stream, mask, mkbf);
    hipLaunchKernelGGL(transpose_w_kernel, dim3(K_ / 64, D_ / 64, 4), dim3(256), 0, stream,
                       Wq, Wk, Wv, Wo, WTq, WTk, WTv, WTo);
    hipLaunchKernelGGL(proj_qkv_kernel, dim3(BS_ / 128, D_ / 128, 3), dim3(256), 0, stream,
                       Xb, WTq, bq, WTk, bk, WTv, bv, emo, mask, q_ws, k_ws, v_ws);
    hipLaunchKernelGGL(attn_kernel, dim3(B_ * H_, S_ / 128), dim3(256), 0, stream,
                       q_ws, k_ws, v_ws, mkbf, ctx);
    hipLaunchKernelGGL(proj_out_kernel, dim3(BS_ / 64, D_ / 128), dim3(256), 0, stream,
                       ctx, WTo, bo, out);
}

// Round 11
// 232.466 us; speedup vs baseline: 1.0673x; 1.0063x over previous
//
#include <hip/hip_runtime.h>
#include <hip/hip_bf16.h>

// Problem: AdvancedAttentionLayer  B=2, S=2048, D=1024, H=16, DH=64
// Round 11: (a) 3 prep kernels fused into one block-range-partitioned
// kernel (fewer graph nodes/gaps); (b) proj_out reverted to 128x128 tile
// (r7's 64x128 halved MFMA density per staged byte and was never isolated).
// attn kept at round-10 (128 q-rows/block, fixed-base softmax, swizzled LDS).

#define B_  2
#define S_  2048
#define D_  1024
#define K_  1024
#define H_  16
#define DH_ 64
#define BS_ (B_*S_)

typedef __hip_bfloat16 bf16;
typedef __attribute__((ext_vector_type(8))) short s8v;   // 8 bf16 = 4 VGPRs
typedef __attribute__((ext_vector_type(4))) short s4v;   // 4 bf16
typedef __attribute__((ext_vector_type(4))) float f4v;   // MFMA C/D

__device__ __forceinline__ float b2f(bf16 x) { return __bfloat162float(x); }
__device__ __forceinline__ bf16  f2b(float x) { return __float2bfloat16(x); }

__device__ __forceinline__ void gl_lds_16B(const bf16* g, bf16* l) {
    __builtin_amdgcn_global_load_lds(
        (const __attribute__((address_space(1))) unsigned int*)g,
        (__attribute__((address_space(3))) unsigned int*)l, 16, 0, 0);
}

// 0.125 * log2(e): folded QK^T scale so softmax uses raw exp2
#define QSCALE_ 0.1803368801f

// ---------------------------------------------------------------------------
// Fused prep kernel. Grid 5136 blocks x 256:
//   blocks [0,1024):    W transpose, z = blk>>8 (Wq/Wk/Wv/Wo), 64x64 tiles
//   blocks [1024,5120): X fp32 -> bf16, 1024 elems per block
//   blocks [5120,5136): mask int32 -> bf16 0/1
// ---------------------------------------------------------------------------
__global__ __launch_bounds__(256) void prep_kernel(
    const float* __restrict__ X, const int* __restrict__ mask,
    const float* __restrict__ Wq, const float* __restrict__ Wk,
    const float* __restrict__ Wv, const float* __restrict__ Wo,
    bf16* __restrict__ Xb, bf16* __restrict__ mkbf,
    bf16* __restrict__ WTq, bf16* __restrict__ WTk,
    bf16* __restrict__ WTv, bf16* __restrict__ WTo)
{
    __shared__ float Ls[64][68];
    const int blk = blockIdx.x;
    const int t   = threadIdx.x;

    if (blk < 1024) {
        const int z   = blk >> 8;
        const int t16 = blk & 255;
        const int k0  = (t16 >> 4) * 64;
        const int n0  = (t16 & 15) * 64;
        const float* __restrict__ W = (z == 0) ? Wq : (z == 1) ? Wk : (z == 2) ? Wv : Wo;
        bf16* __restrict__ WT       = (z == 0) ? WTq : (z == 1) ? WTk : (z == 2) ? WTv : WTo;

        const int lr = t >> 4;
        const int lc = (t & 15) * 4;
        #pragma unroll
        for (int i = 0; i < 4; i++) {
            const int k = i * 16 + lr;
            const float4 v = *(const float4*)(W + (size_t)(k0 + k) * K_ + n0 + lc);
            Ls[k][lc + 0] = v.x; Ls[k][lc + 1] = v.y;
            Ls[k][lc + 2] = v.z; Ls[k][lc + 3] = v.w;
        }
        __syncthreads();
        #pragma unroll
        for (int i = 0; i < 4; i++) {
            const int n = i * 16 + lr;
            s4v o;
            #pragma unroll
            for (int j = 0; j < 4; j++) {
                bf16 tb = f2b(Ls[lc + j][n]);
                o[j] = *(short*)&tb;
            }
            *(s4v*)(WT + (size_t)(n0 + n) * K_ + k0 + lc) = o;
        }
    } else if (blk < 5120) {
        const size_t idx = ((size_t)(blk - 1024) * 256 + t) * 4;
        const float4 v = *(const float4*)(X + idx);
        bf16 t0 = f2b(v.x), t1 = f2b(v.y), t2 = f2b(v.z), t3 = f2b(v.w);
        s4v o;
        o[0] = *(short*)&t0; o[1] = *(short*)&t1;
        o[2] = *(short*)&t2; o[3] = *(short*)&t3;
        *(s4v*)(Xb + idx) = o;
    } else {
        const int idx = (blk - 5120) * 256 + t;
        mkbf[idx] = f2b(mask[idx] ? 1.0f : 0.0f);
    }
}

// ---------------------------------------------------------------------------
// MFMA GEMM core, 128x128 tile (m97 structure). SWAPPED -> C^T layout.
// ---------------------------------------------------------------------------
template <bool SWAPPED>
__device__ __forceinline__ void gemm_tile(
    const bf16* __restrict__ A, const bf16* __restrict__ BT,
    int m0, int n0, bf16* As, bf16* Bs, f4v acc[4][4])
{
    const int t    = threadIdx.x;
    const int lane = t & 63;
    const int wave = t >> 6;
    const int quad = lane >> 4;
    const int l15  = lane & 15;
    const int wr   = wave >> 1;
    const int wc   = wave & 1;

    const int sr = t >> 3;
    const int sc = (t & 7) * 8;

    for (int kb = 0; kb < K_; kb += 64) {
        #pragma unroll
        for (int i = 0; i < 4; i++) {
            const int r = i * 32 + sr;
            gl_lds_16B(A  + (size_t)(m0 + r) * K_ + kb + sc, As + r * 64 + sc);
            gl_lds_16B(BT + (size_t)(n0 + r) * K_ + kb + sc, Bs + r * 64 + sc);
        }
        __syncthreads();

        #pragma unroll
        for (int ks = 0; ks < 2; ks++) {
            s8v fA[4], fB[4];
            #pragma unroll
            for (int i = 0; i < 4; i++) {
                fA[i] = *(const s8v*)&As[(wr * 64 + i * 16 + l15) * 64 + ks * 32 + quad * 8];
                fB[i] = *(const s8v*)&Bs[(wc * 64 + i * 16 + l15) * 64 + ks * 32 + quad * 8];
            }
            #pragma unroll
            for (int i = 0; i < 4; i++)
                #pragma unroll
                for (int j = 0; j < 4; j++)
                    acc[i][j] = SWAPPED
                        ? __builtin_amdgcn_mfma_f32_16x16x32_bf16(fB[i], fA[j], acc[i][j], 0, 0, 0)
                        : __builtin_amdgcn_mfma_f32_16x16x32_bf16(fA[i], fB[j], acc[i][j], 0, 0, 0);
        }
        __syncthreads();
    }
}

// ---------------------------------------------------------------------------
// QKV projection via MFMA. Grid (32, 8, 3), block 256.
// ---------------------------------------------------------------------------
__global__ __launch_bounds__(256) void proj_qkv_kernel(
    const bf16* __restrict__ Xb,
    const bf16* __restrict__ WTq, const float* __restrict__ bq,
    const bf16* __restrict__ WTk, const float* __restrict__ bk,
    const bf16* __restrict__ WTv, const float* __restrict__ bv,
    const float* __restrict__ emo, const int* __restrict__ mask,
    bf16* __restrict__ q_ws, bf16* __restrict__ k_ws, bf16* __restrict__ v_ws)
{
    const int m0 = blockIdx.x * 128;
    const int n0 = blockIdx.y * 128;
    const int z  = blockIdx.z;

    __shared__ __align__(16) bf16 As[128 * 64];
    __shared__ __align__(16) bf16 Bs[128 * 64];

    const int t    = threadIdx.x;
    const int lane = t & 63;
    const int wave = t >> 6;
    const int quad = lane >> 4;
    const int l15  = lane & 15;
    const int wr   = wave >> 1;
    const int wc   = wave & 1;

    f4v acc[4][4] = {};

    if (z == 0) {
        gemm_tile<false>(Xb, WTq, m0, n0, As, Bs, acc);
        #pragma unroll
        for (int j = 0; j < 4; j++) {
            const int n  = n0 + wc * 64 + j * 16 + l15;
            const int h  = n >> 6, dh = n & 63;
            const float bias_n = bq[n] + emo[n];
            #pragma unroll
            for (int i = 0; i < 4; i++) {
                #pragma unroll
                for (int r = 0; r < 4; r++) {
                    const int m = m0 + wr * 64 + i * 16 + quad * 4 + r;
                    const int b = m >> 11, s = m & 2047;
                    q_ws[(((size_t)(b * H_ + h)) * S_ + s) * DH_ + dh] =
                        f2b((acc[i][j][r] + bias_n) * QSCALE_);
                }
            }
        }
    } else if (z == 1) {
        gemm_tile<false>(Xb, WTk, m0, n0, As, Bs, acc);
        #pragma unroll
        for (int j = 0; j < 4; j++) {
            const int n  = n0 + wc * 64 + j * 16 + l15;
            const int h  = n >> 6, dh = n & 63;
            const float bias_n = bk[n];
            #pragma unroll
            for (int i = 0; i < 4; i++) {
                #pragma unroll
                for (int r = 0; r < 4; r++) {
                    const int m = m0 + wr * 64 + i * 16 + quad * 4 + r;
                    const int b = m >> 11, s = m & 2047;
                    k_ws[(((size_t)(b * H_ + h)) * S_ + s) * DH_ + dh] =
                        f2b(acc[i][j][r] + bias_n);
                }
            }
        }
    } else {
        gemm_tile<true>(Xb, WTv, m0, n0, As, Bs, acc);
        #pragma unroll
        for (int j = 0; j < 4; j++) {
            const int m = m0 + wr * 64 + j * 16 + l15;
            const int b = m >> 11, s = m & 2047;
            const float msk = mask[b * S_ + s] ? 1.0f : 0.0f;
            #pragma unroll
            for (int i = 0; i < 4; i++) {
                #pragma unroll
                for (int r = 0; r < 4; r++) {
                    const int n  = n0 + wc * 64 + i * 16 + quad * 4 + r;
                    const int h  = n >> 6, dh = n & 63;
                    v_ws[(((size_t)(b * H_ + h)) * DH_ + dh) * S_ + s] =
                        f2b((acc[i][j][r] + bv[n]) * msk);
                }
            }
        }
    }
}

// ---------------------------------------------------------------------------
// Output projection: 128x128 tile, grid (32, 8). out = ctx @ Wo + bo (fp32).
// ---------------------------------------------------------------------------
__global__ __launch_bounds__(256) void proj_out_kernel(
    const bf16* __restrict__ ctx, const bf16* __restrict__ WTo,
    const float* __restrict__ bo, float* __restrict__ out)
{
    const int m0 = blockIdx.x * 128;
    const int n0 = blockIdx.y * 128;

    __shared__ __align__(16) bf16 As[128 * 64];
    __shared__ __align__(16) bf16 Bs[128 * 64];

    const int t    = threadIdx.x;
    const int lane = t & 63;
    const int wave = t >> 6;
    const int quad = lane >> 4;
    const int l15  = lane & 15;
    const int wr   = wave >> 1;
    const int wc   = wave & 1;

    f4v acc[4][4] = {};
    gemm_tile<false>(ctx, WTo, m0, n0, As, Bs, acc);

    #pragma unroll
    for (int j = 0; j < 4; j++) {
        const int n = n0 + wc * 64 + j * 16 + l15;
        const float bias_n = bo[n];
        #pragma unroll
        for (int i = 0; i < 4; i++) {
            #pragma unroll
            for (int r = 0; r < 4; r++) {
                const int m = m0 + wr * 64 + i * 16 + quad * 4 + r;
                out[(size_t)m * D_ + n] = acc[i][j][r] + bias_n;
            }
        }
    }
}

// ---------------------------------------------------------------------------
// MFMA flash attention (round-10): 128 q-rows/block, fixed-base softmax.
// Grid (B*H=32, S/128=16), block 256 = 4 waves; wave owns 32 q (2 subtiles).
// ---------------------------------------------------------------------------
#define PP_ 88   // p_lds row stride in bf16

__global__ __launch_bounds__(256) void attn_kernel(
    const bf16* __restrict__ q_ws, const bf16* __restrict__ k_ws,
    const bf16* __restrict__ v_ws, const bf16* __restrict__ mkbf,
    bf16* __restrict__ ctx)
{
    const int bh = blockIdx.x;
    const int q0 = blockIdx.y * 128;
    const int b  = bh >> 4;
    const int h  = bh & 15;

    __shared__ __align__(16) bf16 k_lds[64 * 64];     // [key][d], swizzled
    __shared__ __align__(16) bf16 vt_lds[64 * 64];    // [d][key], swizzled
    __shared__ __align__(16) bf16 p_lds[4][32 * PP_]; // per-wave [q][key]

    const int t    = threadIdx.x;
    const int wave = t >> 6;
    const int lane = t & 63;
    const int quad = lane >> 4;
    const int l15  = lane & 15;
    const int lxor = l15 & 7;        // swizzle term for fragment reads

    // ---- Q as B-operand frags (q = q0 + wave*32 + qs*16 + l15), global ----
    s8v qf[2][2];
    #pragma unroll
    for (int qs = 0; qs < 2; qs++)
        #pragma unroll
        for (int dt = 0; dt < 2; dt++)
            qf[qs][dt] = *(const s8v*)(q_ws +
                ((size_t)bh * S_ + q0 + wave * 32 + qs * 16 + l15) * DH_ + dt * 32 + quad * 8);

    f4v oacc[2][4] = {};     // [qs][nt]: rows q (quad*4+r), cols dh (nt*16+l15)
    f4v osum[2]    = {};     // denominators

    // swizzled staging source indices (per-lane constants)
    int srw[2], scs[2];
    #pragma unroll
    for (int c = 0; c < 2; c++) {
        const int e = c * 2048 + t * 8;
        srw[c] = e >> 6;                          // tile row
        scs[c] = ((e >> 3) & 7) ^ (srw[c] & 7);   // source chunk (swizzled)
    }

    for (int kb0 = 0; kb0 < S_; kb0 += 64) {
        // ---- stage K, Vt via global_load_lds with XOR-swizzled sources ----
        #pragma unroll
        for (int c = 0; c < 2; c++) {
            const int e = c * 2048 + t * 8;
            const int r = srw[c], cs = scs[c];
            gl_lds_16B(k_ws + ((size_t)bh * S_ + kb0) * DH_ + r * 64 + cs * 8,
                       k_lds + e);
            gl_lds_16B(v_ws + ((size_t)bh * DH_ + r) * S_ + kb0 + cs * 8,
                       vt_lds + e);
        }
        __syncthreads();

        // ---- S^T = K Q^T : 4 key-tiles x 2 d-halves x 2 q-subtiles ----
        f4v sacc[2][4] = {};
        #pragma unroll
        for (int kt = 0; kt < 4; kt++) {
            #pragma unroll
            for (int dt = 0; dt < 2; dt++) {
                const s8v kf = *(const s8v*)&k_lds[(kt * 16 + l15) * 64 +
                                                   ((dt * 4 + quad) ^ lxor) * 8];
                #pragma unroll
                for (int qs = 0; qs < 2; qs++)
                    sacc[qs][kt] = __builtin_amdgcn_mfma_f32_16x16x32_bf16(kf, qf[qs][dt], sacc[qs][kt], 0, 0, 0);
            }
        }

        // ---- fixed-base softmax numerators: p = exp2(s), straight to LDS ----
        #pragma unroll
        for (int qs = 0; qs < 2; qs++) {
            #pragma unroll
            for (int kt = 0; kt < 4; kt++) {
                float2 e01, e23;
                e01.x = exp2f(sacc[qs][kt][0]);
                e01.y = exp2f(sacc[qs][kt][1]);
                e23.x = exp2f(sacc[qs][kt][2]);
                e23.y = exp2f(sacc[qs][kt][3]);
                union { __hip_bfloat162 hh; unsigned u; } lo, hi;
                lo.hh = __float22bfloat162_rn(e01);
                hi.hh = __float22bfloat162_rn(e23);
                *(uint2*)&p_lds[wave][(qs * 16 + l15) * PP_ + kt * 16 + quad * 4] =
                    make_uint2(lo.u, hi.u);
            }
        }

        // p_lds is wave-private: need only LDS drain, no barrier
        __builtin_amdgcn_s_waitcnt(0xC07F);

        // ---- O += P V ; denominator += P maskvec ----
        #pragma unroll
        for (int kh = 0; kh < 2; kh++) {
            s8v ap[2];
            #pragma unroll
            for (int qs = 0; qs < 2; qs++)
                ap[qs] = *(const s8v*)&p_lds[wave][(qs * 16 + l15) * PP_ + kh * 32 + quad * 8];
            const s8v mv = *(const s8v*)(mkbf + (size_t)b * S_ + kb0 + kh * 32 + quad * 8);
            #pragma unroll
            for (int nt = 0; nt < 4; nt++) {
                const s8v vf = *(const s8v*)&vt_lds[(nt * 16 + l15) * 64 +
                                                    ((kh * 4 + quad) ^ lxor) * 8];
                #pragma unroll
                for (int qs = 0; qs < 2; qs++)
                    oacc[qs][nt] = __builtin_amdgcn_mfma_f32_16x16x32_bf16(ap[qs], vf, oacc[qs][nt], 0, 0, 0);
            }
            #pragma unroll
            for (int qs = 0; qs < 2; qs++)
                osum[qs] = __builtin_amdgcn_mfma_f32_16x16x32_bf16(ap[qs], mv, osum[qs], 0, 0, 0);
        }
        __syncthreads();   // protect k_lds/vt_lds before next staging
    }

    // ---- epilogue ----
    #pragma unroll
    for (int qs = 0; qs < 2; qs++) {
        #pragma unroll
        for (int r = 0; r < 4; r++) {
            const float inv = 1.0f / osum[qs][r];
            const int q = q0 + wave * 32 + qs * 16 + quad * 4 + r;
            #pragma unroll
            for (int nt = 0; nt < 4; nt++)
                ctx[((size_t)b * S_ + q) * D_ + h * DH_ + nt * 16 + l15] =
                    f2b(oacc[qs][nt][r] * inv);
        }
    }
}

// ---------------------------------------------------------------------------
extern "C" void kernel_launch(void* const* d_in, const int* in_sizes, int n_in,
                              void* d_out, int out_size, void* d_ws, size_t ws_size,
                              hipStream_t stream) {
    (void)in_sizes; (void)n_in; (void)out_size; (void)ws_size;

    const float* X    = (const float*)d_in[0];
    const int*   mask = (const int*)d_in[1];
    const float* Wq   = (const float*)d_in[2];
    const float* bq   = (const float*)d_in[3];
    const float* Wk   = (const float*)d_in[4];
    const float* bk   = (const float*)d_in[5];
    const float* Wv   = (const float*)d_in[6];
    const float* bv   = (const float*)d_in[7];
    const float* emo  = (const float*)d_in[8];
    const float* Wo   = (const float*)d_in[9];
    const float* bo   = (const float*)d_in[10];
    float* out = (float*)d_out;

    bf16* q_ws = (bf16*)d_ws;                       // [B,H,S,DH]   8 MB
    bf16* k_ws = q_ws + (size_t)BS_ * D_;           // [B,H,S,DH]   8 MB
    bf16* v_ws = k_ws + (size_t)BS_ * D_;           // [B,H,DH,S]   8 MB
    bf16* ctx  = v_ws + (size_t)BS_ * D_;           // [B,S,D]      8 MB
    bf16* Xb   = ctx  + (size_t)BS_ * D_;           // [BS,D]       8 MB
    bf16* WTq  = Xb   + (size_t)BS_ * D_;           // [N,K]        2 MB
    bf16* WTk  = WTq  + (size_t)D_ * K_;
    bf16* WTv  = WTk  + (size_t)D_ * K_;
    bf16* WTo  = WTv  + (size_t)D_ * K_;
    bf16* mkbf = WTo  + (size_t)D_ * K_;            // [B*S] bf16 mask

    hipLaunchKernelGGL(prep_kernel, dim3(5136), dim3(256), 0, stream,
                       X, mask, Wq, Wk, Wv, Wo, Xb, mkbf, WTq, WTk, WTv, WTo);
    hipLaunchKernelGGL(proj_qkv_kernel, dim3(BS_ / 128, D_ / 128, 3), dim3(256), 0, stream,
                       Xb, WTq, bq, WTk, bk, WTv, bv, emo, mask, q_ws, k_ws, v_ws);
    hipLaunchKernelGGL(attn_kernel, dim3(B_ * H_, S_ / 128), dim3(256), 0, stream,
                       q_ws, k_ws, v_ws, mkbf, ctx);
    hipLaunchKernelGGL(proj_out_kernel, dim3(BS_ / 128, D_ / 128), dim3(256), 0, stream,
                       ctx, WTo, bo, out);
}